// Round 10
// baseline (165.765 us; speedup 1.0000x reference)
//
#include <hip/hip_runtime.h>
#include <hip/hip_fp16.h>

typedef unsigned short u16;
typedef unsigned int u32;
typedef unsigned long long u64;

#define VOCAB 50000
#define BATCH 2048
#define NTOP 64
#define RHO 0.1f

#define KSPLIT 32
#define CHUNK 1568          // 24x64+32; chunk 31: 48608..50000 = 21x64 + 48
#define KSTEP 64

typedef short bf16x4 __attribute__((ext_vector_type(4)));
typedef short bf16x8 __attribute__((ext_vector_type(8)));
typedef float f32x4 __attribute__((ext_vector_type(4)));

__device__ __forceinline__ u32 cvtpk(float lo, float hi) {
  u32 r;
  asm volatile("v_cvt_pk_bf16_f32 %0, %1, %2" : "=v"(r) : "v"(lo), "v"(hi));
  return r;
}
union frag_cast { bf16x4 h[2]; bf16x8 v; };

// GEMM (R9 structure, prefetch depth 2 -> 3):
// sp[bx] = x[rows, chunk bx] @ beta[:, chunk bx]^T via bf16 MFMA.
// x: THREE register sets (xA/xB/xC), each 4 float4 -> 24 x-loads in flight
//    per wave (3 k-steps ahead) to deepen HBM queue occupancy further.
// beta: 1-deep reg staging (L2-resident; chunk bx's 32 row-blocks land on
//    XCD bx%8, so beta is HBM-fetched once per chunk).
// LDS [r][k] bf16 dbuf, byte = r*128 + (2k ^ ((r&7)<<4)); 1 barrier/step.
__global__ void __launch_bounds__(256, 4) ctm_gemm(const float* __restrict__ x,
                                                   const float* __restrict__ beta,
                                                   __half* __restrict__ sp) {
  __shared__ u16 ldsX[2][64 * KSTEP];   // 8KB per buffer
  __shared__ u16 ldsB[2][64 * KSTEP];

  const int t = threadIdx.x;
  const int l = t & 63;
  const int w = t >> 6;
  const int fr = l & 15;
  const int fk = l >> 4;

  const int bx = blockIdx.x;
  const int k0 = bx * CHUNK;
  const int kend = (k0 + CHUNK < VOCAB) ? (k0 + CHUNK) : VOCAB;
  const int row0 = blockIdx.y * 64;
  const int nsteps = (kend - k0 + KSTEP - 1) >> 6;   // 25, or 22 on chunk 31

  // Staging map: c = t&15 k-quad, srow = t>>4 covers rows {srow,+16,+32,+48}.
  const int c = t & 15;
  const int srow = t >> 4;
  const float* xb = x + (u64)(row0 + srow) * VOCAB + k0 + c * 4;
  const float* betab = beta + (u64)srow * VOCAB + k0 + c * 4;
  const u32 wofs = (u32)(srow * 128) + (((u32)(c * 8)) ^ ((u32)((srow & 7) << 4)));

  // Fragment-read constants
  const int arow = w * 16 + fr;
  const u32 arb = (u32)(arow * 128);
  const u32 aswz = (u32)((arow & 7) << 4);

  f32x4 acc[4] = {{0.f,0.f,0.f,0.f},{0.f,0.f,0.f,0.f},{0.f,0.f,0.f,0.f},{0.f,0.f,0.f,0.f}};

  float4 xA0, xA1, xA2, xA3;   // 3-deep x sets
  float4 xB0, xB1, xB2, xB3;
  float4 xC0, xC1, xC2, xC3;
  float4 bb0, bb1, bb2, bb3;   // 1-deep beta set

#define LOADX(S0, S1, S2, S3, st)                                            \
  {                                                                          \
    const int rem_ = kend - k0 - (st) * KSTEP;                               \
    S0 = S1 = S2 = S3 = make_float4(0.f, 0.f, 0.f, 0.f);                     \
    if (c * 4 < rem_) {                                                      \
      const float* p_ = xb + (st) * KSTEP;                                   \
      S0 = *(const float4*)(p_);                                             \
      S1 = *(const float4*)(p_ + 16 * VOCAB);                                \
      S2 = *(const float4*)(p_ + 32 * VOCAB);                                \
      S3 = *(const float4*)(p_ + 48 * VOCAB);                                \
    }                                                                        \
  }

#define LOADB(st)                                                            \
  {                                                                          \
    const int rem_ = kend - k0 - (st) * KSTEP;                               \
    bb0 = bb1 = bb2 = bb3 = make_float4(0.f, 0.f, 0.f, 0.f);                 \
    if (c * 4 < rem_) {                                                      \
      const float* p_ = betab + (st) * KSTEP;                                \
      bb0 = *(const float4*)(p_);                                            \
      bb1 = *(const float4*)(p_ + 16 * VOCAB);                               \
      bb2 = *(const float4*)(p_ + 32 * VOCAB);                               \
      bb3 = *(const float4*)(p_ + 48 * VOCAB);                               \
    }                                                                        \
  }

#define WRITE(S0, S1, S2, S3, bi)                                            \
  {                                                                          \
    char* nX = (char*)ldsX[bi];                                              \
    char* nB = (char*)ldsB[bi];                                              \
    *(uint2*)(nX + wofs)        = make_uint2(cvtpk(S0.x, S0.y), cvtpk(S0.z, S0.w)); \
    *(uint2*)(nX + wofs + 2048) = make_uint2(cvtpk(S1.x, S1.y), cvtpk(S1.z, S1.w)); \
    *(uint2*)(nX + wofs + 4096) = make_uint2(cvtpk(S2.x, S2.y), cvtpk(S2.z, S2.w)); \
    *(uint2*)(nX + wofs + 6144) = make_uint2(cvtpk(S3.x, S3.y), cvtpk(S3.z, S3.w)); \
    *(uint2*)(nB + wofs)        = make_uint2(cvtpk(bb0.x, bb0.y), cvtpk(bb0.z, bb0.w)); \
    *(uint2*)(nB + wofs + 2048) = make_uint2(cvtpk(bb1.x, bb1.y), cvtpk(bb1.z, bb1.w)); \
    *(uint2*)(nB + wofs + 4096) = make_uint2(cvtpk(bb2.x, bb2.y), cvtpk(bb2.z, bb2.w)); \
    *(uint2*)(nB + wofs + 6144) = make_uint2(cvtpk(bb3.x, bb3.y), cvtpk(bb3.z, bb3.w)); \
  }

#define COMPUTE(bi)                                                          \
  {                                                                          \
    const char* bufA = (const char*)ldsX[bi];                                \
    const char* bufB = (const char*)ldsB[bi];                                \
    _Pragma("unroll")                                                        \
    for (int s_ = 0; s_ < 2; ++s_) {                                         \
      const u32 in0 = (u32)(s_ * 64 + fk * 8);                               \
      const u32 in1 = in0 + 32;                                              \
      frag_cast ua;                                                          \
      ua.h[0] = *(const bf16x4*)(bufA + arb + (in0 ^ aswz));                 \
      ua.h[1] = *(const bf16x4*)(bufA + arb + (in1 ^ aswz));                 \
      _Pragma("unroll")                                                      \
      for (int n_ = 0; n_ < 4; ++n_) {                                       \
        const int bcol = (n_ << 4) | fr;                                     \
        const u32 brb = (u32)(bcol * 128);                                   \
        const u32 bswz = (u32)((bcol & 7) << 4);                             \
        frag_cast ub;                                                        \
        ub.h[0] = *(const bf16x4*)(bufB + brb + (in0 ^ bswz));               \
        ub.h[1] = *(const bf16x4*)(bufB + brb + (in1 ^ bswz));               \
        acc[n_] = __builtin_amdgcn_mfma_f32_16x16x32_bf16(ua.v, ub.v, acc[n_], 0, 0, 0); \
      }                                                                      \
    }                                                                        \
  }

  // PHASE for step st consuming x-set S (holds step st+1), reloading st+4.
#define PHASE(S0, S1, S2, S3)                                                \
    if (st + 1 < nsteps) LOADB(st + 1);                                      \
    COMPUTE(st & 1);                                                         \
    if (st + 1 < nsteps) WRITE(S0, S1, S2, S3, (st + 1) & 1);                \
    if (st + 4 < nsteps) LOADX(S0, S1, S2, S3, st + 4);                      \
    if (st + 1 < nsteps) __syncthreads();                                    \
    if (++st >= nsteps) break;

  // ---- prologue: stage step 0; preload x for steps 1,2,3 (nsteps >= 22) ----
  LOADX(xA0, xA1, xA2, xA3, 0);
  LOADB(0);
  WRITE(xA0, xA1, xA2, xA3, 0);
  LOADX(xA0, xA1, xA2, xA3, 1);
  LOADX(xB0, xB1, xB2, xB3, 2);
  LOADX(xC0, xC1, xC2, xC3, 3);
  __syncthreads();

  // ---- main loop: set rotation A,B,C (period 3); buffer parity via st&1 ----
  int st = 0;
  while (true) {
    PHASE(xA0, xA1, xA2, xA3)
    PHASE(xB0, xB1, xB2, xB3)
    PHASE(xC0, xC1, xC2, xC3)
  }

  // C-write: f16 partials; row = w*16 + fk*4 + r, col = n*16 + fr
  __half* spb = sp + (u64)bx * (BATCH * NTOP);
  const int orow = row0 + w * 16 + fk * 4;
  #pragma unroll
  for (int n = 0; n < 4; ++n) {
    #pragma unroll
    for (int r = 0; r < 4; ++r)
      spb[(u64)(orow + r) * NTOP + ((n << 4) | fr)] = __float2half(acc[n][r]);
  }
#undef LOADX
#undef LOADB
#undef WRITE
#undef COMPUTE
#undef PHASE
}

// Epilogue: reduce 32 f16 partials, then out = s + mu + RHO*(s @ theta_offdiag^T)
__global__ void __launch_bounds__(256) ctm_epi(const __half* __restrict__ sp,
                                               const float* __restrict__ theta,
                                               const float* __restrict__ mu,
                                               float* __restrict__ out) {
  __shared__ float thT[NTOP * NTOP];   // thT[j*64+k] = theta[k][j]
  __shared__ float sb[8 * NTOP];
  const int t = threadIdx.x;
  const int r0 = blockIdx.x * 8;

  #pragma unroll
  for (int i = 0; i < 16; ++i) {
    int e = i * 256 + t;
    thT[(e & 63) * 64 + (e >> 6)] = theta[e];
  }

  const int k = t & 63;
  const int rl = t >> 6;
  #pragma unroll
  for (int rr = 0; rr < 2; ++rr) {
    const int r = rl + rr * 4;
    float sum = 0.f;
    #pragma unroll
    for (int cc = 0; cc < KSPLIT; ++cc)
      sum += __half2float(sp[(u64)cc * (BATCH * NTOP) + (u64)(r0 + r) * NTOP + k]);
    sb[r * 64 + k] = sum;
  }
  __syncthreads();

  const float muk = mu[k];
  const float diag = thT[k * 64 + k];
  #pragma unroll
  for (int rr = 0; rr < 2; ++rr) {
    const int r = rl + rr * 4;
    const float* srow = &sb[r * 64];
    float accv = 0.f;
    #pragma unroll 8
    for (int j = 0; j < 64; ++j)
      accv += thT[j * 64 + k] * srow[j];
    const float sv = srow[k];
    out[(r0 + r) * 64 + k] = sv + muk + RHO * (accv - diag * sv);
  }
}

extern "C" void kernel_launch(void* const* d_in, const int* in_sizes, int n_in,
                              void* d_out, int out_size, void* d_ws, size_t ws_size,
                              hipStream_t stream) {
  const float* x = (const float*)d_in[0];
  const float* beta = (const float*)d_in[1];
  const float* theta = (const float*)d_in[2];
  const float* mu = (const float*)d_in[3];
  float* out = (float*)d_out;

  // ws: sp f16 [KSPLIT][BATCH][NTOP] = 8.39MB; fully written each launch.
  __half* sp = (__half*)d_ws;

  ctm_gemm<<<dim3(KSPLIT, BATCH / 64), 256, 0, stream>>>(x, beta, sp);
  ctm_epi<<<BATCH / 8, 256, 0, stream>>>(sp, theta, mu, out);
}

// Round 11
// 101.251 us; speedup vs baseline: 1.6372x; 1.6372x over previous
//
#include <hip/hip_runtime.h>
#include <hip/hip_fp16.h>

typedef unsigned short u16;
typedef unsigned int u32;
typedef unsigned long long u64;

#define VOCAB 50000
#define BATCH 2048
#define NTOP 64
#define RHO 0.1f

#define KSPLIT 32
#define CHUNK 1568          // 24x64+32; chunk 31: 48608..50000 = 21x64 + 48
#define KSTEP 64

typedef short bf16x4 __attribute__((ext_vector_type(4)));
typedef short bf16x8 __attribute__((ext_vector_type(8)));
typedef float f32x4 __attribute__((ext_vector_type(4)));

__device__ __forceinline__ u32 cvtpk(float lo, float hi) {
  u32 r;
  asm volatile("v_cvt_pk_bf16_f32 %0, %1, %2" : "=v"(r) : "v"(lo), "v"(hi));
  return r;
}
union frag_cast { bf16x4 h[2]; bf16x8 v; };

// GEMM (R9 = best: R4 structure + 2-deep x prefetch + f16 partials):
// sp[bx] = x[rows, chunk bx] @ beta[:, chunk bx]^T via bf16 MFMA.
// x: TWO register sets (xA*/xB*), each 4 float4 -> 16 x-loads in flight per
//    wave (2 k-steps ahead). Depth 3 spills past the 128-VGPR cap (R10: 1.6x
//    regression) — depth 2 is the saturation point at 4 blocks/CU.
// beta: 1-deep reg staging (L2-resident; chunk bx's 32 row-blocks land on
//    XCD bx%8, so beta is HBM-fetched once per chunk).
// LDS [r][k] bf16 dbuf, byte = r*128 + (2k ^ ((r&7)<<4)); 1 barrier/step.
__global__ void __launch_bounds__(256, 4) ctm_gemm(const float* __restrict__ x,
                                                   const float* __restrict__ beta,
                                                   __half* __restrict__ sp) {
  __shared__ u16 ldsX[2][64 * KSTEP];   // 8KB per buffer
  __shared__ u16 ldsB[2][64 * KSTEP];

  const int t = threadIdx.x;
  const int l = t & 63;
  const int w = t >> 6;
  const int fr = l & 15;
  const int fk = l >> 4;

  const int bx = blockIdx.x;
  const int k0 = bx * CHUNK;
  const int kend = (k0 + CHUNK < VOCAB) ? (k0 + CHUNK) : VOCAB;
  const int row0 = blockIdx.y * 64;
  const int nsteps = (kend - k0 + KSTEP - 1) >> 6;   // 25, or 22 on chunk 31

  // Staging map: c = t&15 k-quad, srow = t>>4 covers rows {srow,+16,+32,+48}.
  const int c = t & 15;
  const int srow = t >> 4;
  const float* xb = x + (u64)(row0 + srow) * VOCAB + k0 + c * 4;
  const float* betab = beta + (u64)srow * VOCAB + k0 + c * 4;
  const u32 wofs = (u32)(srow * 128) + (((u32)(c * 8)) ^ ((u32)((srow & 7) << 4)));

  // Fragment-read constants
  const int arow = w * 16 + fr;
  const u32 arb = (u32)(arow * 128);
  const u32 aswz = (u32)((arow & 7) << 4);

  f32x4 acc[4] = {{0.f,0.f,0.f,0.f},{0.f,0.f,0.f,0.f},{0.f,0.f,0.f,0.f},{0.f,0.f,0.f,0.f}};

  float4 xA0, xA1, xA2, xA3, xB0, xB1, xB2, xB3;   // 2-deep x sets
  float4 bb0, bb1, bb2, bb3;                        // 1-deep beta set

#define LOADX(S0, S1, S2, S3, st)                                            \
  {                                                                          \
    const int rem_ = kend - k0 - (st) * KSTEP;                               \
    S0 = S1 = S2 = S3 = make_float4(0.f, 0.f, 0.f, 0.f);                     \
    if (c * 4 < rem_) {                                                      \
      const float* p_ = xb + (st) * KSTEP;                                   \
      S0 = *(const float4*)(p_);                                             \
      S1 = *(const float4*)(p_ + 16 * VOCAB);                                \
      S2 = *(const float4*)(p_ + 32 * VOCAB);                                \
      S3 = *(const float4*)(p_ + 48 * VOCAB);                                \
    }                                                                        \
  }

#define LOADB(st)                                                            \
  {                                                                          \
    const int rem_ = kend - k0 - (st) * KSTEP;                               \
    bb0 = bb1 = bb2 = bb3 = make_float4(0.f, 0.f, 0.f, 0.f);                 \
    if (c * 4 < rem_) {                                                      \
      const float* p_ = betab + (st) * KSTEP;                                \
      bb0 = *(const float4*)(p_);                                            \
      bb1 = *(const float4*)(p_ + 16 * VOCAB);                               \
      bb2 = *(const float4*)(p_ + 32 * VOCAB);                               \
      bb3 = *(const float4*)(p_ + 48 * VOCAB);                               \
    }                                                                        \
  }

#define WRITE(S0, S1, S2, S3, bi)                                            \
  {                                                                          \
    char* nX = (char*)ldsX[bi];                                              \
    char* nB = (char*)ldsB[bi];                                              \
    *(uint2*)(nX + wofs)        = make_uint2(cvtpk(S0.x, S0.y), cvtpk(S0.z, S0.w)); \
    *(uint2*)(nX + wofs + 2048) = make_uint2(cvtpk(S1.x, S1.y), cvtpk(S1.z, S1.w)); \
    *(uint2*)(nX + wofs + 4096) = make_uint2(cvtpk(S2.x, S2.y), cvtpk(S2.z, S2.w)); \
    *(uint2*)(nX + wofs + 6144) = make_uint2(cvtpk(S3.x, S3.y), cvtpk(S3.z, S3.w)); \
    *(uint2*)(nB + wofs)        = make_uint2(cvtpk(bb0.x, bb0.y), cvtpk(bb0.z, bb0.w)); \
    *(uint2*)(nB + wofs + 2048) = make_uint2(cvtpk(bb1.x, bb1.y), cvtpk(bb1.z, bb1.w)); \
    *(uint2*)(nB + wofs + 4096) = make_uint2(cvtpk(bb2.x, bb2.y), cvtpk(bb2.z, bb2.w)); \
    *(uint2*)(nB + wofs + 6144) = make_uint2(cvtpk(bb3.x, bb3.y), cvtpk(bb3.z, bb3.w)); \
  }

#define COMPUTE(bi)                                                          \
  {                                                                          \
    const char* bufA = (const char*)ldsX[bi];                                \
    const char* bufB = (const char*)ldsB[bi];                                \
    _Pragma("unroll")                                                        \
    for (int s_ = 0; s_ < 2; ++s_) {                                         \
      const u32 in0 = (u32)(s_ * 64 + fk * 8);                               \
      const u32 in1 = in0 + 32;                                              \
      frag_cast ua;                                                          \
      ua.h[0] = *(const bf16x4*)(bufA + arb + (in0 ^ aswz));                 \
      ua.h[1] = *(const bf16x4*)(bufA + arb + (in1 ^ aswz));                 \
      _Pragma("unroll")                                                      \
      for (int n_ = 0; n_ < 4; ++n_) {                                       \
        const int bcol = (n_ << 4) | fr;                                     \
        const u32 brb = (u32)(bcol * 128);                                   \
        const u32 bswz = (u32)((bcol & 7) << 4);                             \
        frag_cast ub;                                                        \
        ub.h[0] = *(const bf16x4*)(bufB + brb + (in0 ^ bswz));               \
        ub.h[1] = *(const bf16x4*)(bufB + brb + (in1 ^ bswz));               \
        acc[n_] = __builtin_amdgcn_mfma_f32_16x16x32_bf16(ua.v, ub.v, acc[n_], 0, 0, 0); \
      }                                                                      \
    }                                                                        \
  }

  // ---- prologue: stage step 0; preload x for steps 1 (xA) and 2 (xB) ----
  LOADX(xA0, xA1, xA2, xA3, 0);
  LOADB(0);
  WRITE(xA0, xA1, xA2, xA3, 0);
  LOADX(xA0, xA1, xA2, xA3, 1);
  LOADX(xB0, xB1, xB2, xB3, 2);
  __syncthreads();

  // ---- main loop: phases alternate x-set A/B; 1 barrier per step ----
  // invariant at phase start for step st: the x-set of parity (st+1)&1
  // (A on even st, B on odd) holds step st+1's data.
  int st = 0;
  while (true) {
    // phase A (even st)
    if (st + 1 < nsteps) LOADB(st + 1);
    COMPUTE(st & 1);
    if (st + 1 < nsteps) WRITE(xA0, xA1, xA2, xA3, (st + 1) & 1);
    if (st + 3 < nsteps) LOADX(xA0, xA1, xA2, xA3, st + 3);
    if (st + 1 < nsteps) __syncthreads();
    if (++st >= nsteps) break;

    // phase B (odd st)
    if (st + 1 < nsteps) LOADB(st + 1);
    COMPUTE(st & 1);
    if (st + 1 < nsteps) WRITE(xB0, xB1, xB2, xB3, (st + 1) & 1);
    if (st + 3 < nsteps) LOADX(xB0, xB1, xB2, xB3, st + 3);
    if (st + 1 < nsteps) __syncthreads();
    if (++st >= nsteps) break;
  }

  // C-write: f16 partials; row = w*16 + fk*4 + r, col = n*16 + fr
  __half* spb = sp + (u64)bx * (BATCH * NTOP);
  const int orow = row0 + w * 16 + fk * 4;
  #pragma unroll
  for (int n = 0; n < 4; ++n) {
    #pragma unroll
    for (int r = 0; r < 4; ++r)
      spb[(u64)(orow + r) * NTOP + ((n << 4) | fr)] = __float2half(acc[n][r]);
  }
#undef LOADX
#undef LOADB
#undef WRITE
#undef COMPUTE
}

// Epilogue: reduce 32 f16 partials, then out = s + mu + RHO*(s @ theta_offdiag^T)
__global__ void __launch_bounds__(256) ctm_epi(const __half* __restrict__ sp,
                                               const float* __restrict__ theta,
                                               const float* __restrict__ mu,
                                               float* __restrict__ out) {
  __shared__ float thT[NTOP * NTOP];   // thT[j*64+k] = theta[k][j]
  __shared__ float sb[8 * NTOP];
  const int t = threadIdx.x;
  const int r0 = blockIdx.x * 8;

  #pragma unroll
  for (int i = 0; i < 16; ++i) {
    int e = i * 256 + t;
    thT[(e & 63) * 64 + (e >> 6)] = theta[e];
  }

  const int k = t & 63;
  const int rl = t >> 6;
  #pragma unroll
  for (int rr = 0; rr < 2; ++rr) {
    const int r = rl + rr * 4;
    float sum = 0.f;
    #pragma unroll
    for (int cc = 0; cc < KSPLIT; ++cc)
      sum += __half2float(sp[(u64)cc * (BATCH * NTOP) + (u64)(r0 + r) * NTOP + k]);
    sb[r * 64 + k] = sum;
  }
  __syncthreads();

  const float muk = mu[k];
  const float diag = thT[k * 64 + k];
  #pragma unroll
  for (int rr = 0; rr < 2; ++rr) {
    const int r = rl + rr * 4;
    const float* srow = &sb[r * 64];
    float accv = 0.f;
    #pragma unroll 8
    for (int j = 0; j < 64; ++j)
      accv += thT[j * 64 + k] * srow[j];
    const float sv = srow[k];
    out[(r0 + r) * 64 + k] = sv + muk + RHO * (accv - diag * sv);
  }
}

extern "C" void kernel_launch(void* const* d_in, const int* in_sizes, int n_in,
                              void* d_out, int out_size, void* d_ws, size_t ws_size,
                              hipStream_t stream) {
  const float* x = (const float*)d_in[0];
  const float* beta = (const float*)d_in[1];
  const float* theta = (const float*)d_in[2];
  const float* mu = (const float*)d_in[3];
  float* out = (float*)d_out;

  // ws: sp f16 [KSPLIT][BATCH][NTOP] = 8.39MB; fully written each launch.
  __half* sp = (__half*)d_ws;

  ctm_gemm<<<dim3(KSPLIT, BATCH / 64), 256, 0, stream>>>(x, beta, sp);
  ctm_epi<<<BATCH / 8, 256, 0, stream>>>(sp, theta, mu, out);
}